// Round 6
// baseline (382.612 us; speedup 1.0000x reference)
//
#include <hip/hip_runtime.h>

// EquivariantProductBasisBlock (MACE symmetric contraction, corr=3) + o3.Linear
// N=10000 nodes, C=128 channels, L=9 (lmax=2), E=5 elements, fp32 throughout.
//
// R6 changes vs R5 (contract/table/sort kernels untouched):
//  - linear_kernel: the 4 per-dd dispatches wrote out/read sc with stride-3
//    across lanes (24 partial lines per store-wave, RMW'd by 3 blocks) -> the
//    ~170us residue. Now ONE kernel: block = 16 nodes x 4 dd x 128 co,
//    assemble full 512-float rows in LDS, coalesced float4 sc-read + out-write.

#define CCH 128
#define LDIM 9
#define NE 5
// per (e,c) table: T3[dd][81 rows][12: w0..w8,t2,0,0] | T1[dd][9]
#define T1OFF 3888            // 4*81*12
#define TSTRIDE 3924          // + 4*9 (multiple of 4)
#define NPT 4                 // nodes per thread in contraction kernel
#define BLK 256
#define U3LDS 8748            // max staged U3 slice (729*12 floats)

// ------------------------------------------------------------- sort: count
__global__ __launch_bounds__(BLK) void count_kernel(
    const float* __restrict__ attrs, int N,
    int* __restrict__ elem, int* __restrict__ gcnt) {
  int n = blockIdx.x * BLK + threadIdx.x;
  if (n >= N) return;
  const float* a = attrs + n * NE;
  int e = 0;
#pragma unroll
  for (int j = 1; j < NE; ++j)
    if (a[j] > 0.5f) e = j;
  elem[n] = e;
  int lane = threadIdx.x & 63;
#pragma unroll
  for (int k = 0; k < NE; ++k) {
    unsigned long long m = __ballot(e == k);
    if (m) {
      int leader = __ffsll((long long)m) - 1;
      if (lane == leader) atomicAdd(&gcnt[k], __popcll(m));
    }
  }
}

// ------------------------------------------------------------ sort: prefix
__global__ void offs_kernel(const int* __restrict__ gcnt,
                            int* __restrict__ offs, int* __restrict__ cur) {
  if (threadIdx.x == 0) {
    int acc = 0;
    for (int k = 0; k < NE; ++k) { offs[k] = acc; cur[k] = acc; acc += gcnt[k]; }
    offs[NE] = acc;
  }
}

// ----------------------------------------------------------- sort: scatter
__global__ __launch_bounds__(BLK) void scatter_kernel(
    const int* __restrict__ elem, int N,
    int* __restrict__ cur, int* __restrict__ order) {
  int n = blockIdx.x * BLK + threadIdx.x;
  if (n >= N) return;
  int e = elem[n];
  int lane = threadIdx.x & 63;
#pragma unroll
  for (int k = 0; k < NE; ++k) {
    if (e == k) {
      unsigned long long m = __ballot(1);
      int cnt = __popcll(m);
      int leader = __ffsll((long long)m) - 1;
      int base = 0;
      if (lane == leader) base = atomicAdd(&cur[k], cnt);
      base = __shfl(base, leader);
      int rank = __popcll(m & ((1ull << lane) - 1ull));
      order[base + rank] = n;
    }
  }
}

// --------------------------------- build U (x) w coefficient tables (LDS-staged)
__global__ __launch_bounds__(BLK) void table_kernel(
    const float* __restrict__ U3_0, const float* __restrict__ U2_0,
    const float* __restrict__ U1_0, const float* __restrict__ U3_1,
    const float* __restrict__ U2_1, const float* __restrict__ U1_1,
    const float* __restrict__ w3_0, const float* __restrict__ w2_0,
    const float* __restrict__ w1_0, const float* __restrict__ w3_1,
    const float* __restrict__ w2_1, const float* __restrict__ w1_1,
    float* __restrict__ table) {
  int b = blockIdx.x;              // e*CCH + c
  int e = b / CCH, c = b % CCH;
  float* T = table + (size_t)b * TSTRIDE;
  __shared__ float Us[U3LDS + 324 + 12];   // U3 slice | U2 slice | U1 slice

  // ---- dd = 0 (irrep l=0): U3_0[729][10], U2_0[81][3], U1_0[9]
  for (int i = threadIdx.x; i < 7290; i += BLK) Us[i] = U3_0[i];
  for (int i = threadIdx.x; i < 243; i += BLK)  Us[U3LDS + i] = U2_0[i];
  if (threadIdx.x < 9) Us[U3LDS + 324 + threadIdx.x] = U1_0[threadIdx.x];
  float w3a[10], w2a[3];
#pragma unroll
  for (int k = 0; k < 10; ++k) w3a[k] = w3_0[(e * 10 + k) * CCH + c];
#pragma unroll
  for (int k = 0; k < 3; ++k)  w2a[k] = w2_0[(e * 3 + k) * CCH + c];
  __syncthreads();
  for (int idx = threadIdx.x; idx < 972; idx += BLK) {
    int row = idx / 12, w = idx % 12;      // row = u*9+v
    float acc = 0.f;
    if (w < 9) {
      int r = row * 9 + w;
#pragma unroll
      for (int k = 0; k < 10; ++k) acc += Us[r * 10 + k] * w3a[k];
    } else if (w == 9) {
#pragma unroll
      for (int k = 0; k < 3; ++k) acc += Us[U3LDS + row * 3 + k] * w2a[k];
    }
    T[idx] = acc;                          // coalesced
  }
  if (threadIdx.x < 9)
    T[T1OFF + threadIdx.x] = Us[U3LDS + 324 + threadIdx.x] * w1_0[e * CCH + c];

  // ---- dd = 1..3 (irrep l=1): U3_1[d][729][12], U2_1[d][81][4], U1_1[d][9]
#pragma unroll 1
  for (int d = 0; d < 3; ++d) {
    __syncthreads();                       // all reads of Us done
    for (int i = threadIdx.x; i < 8748; i += BLK) Us[i] = U3_1[d * 8748 + i];
    for (int i = threadIdx.x; i < 324; i += BLK)  Us[U3LDS + i] = U2_1[d * 324 + i];
    if (threadIdx.x < 9) Us[U3LDS + 324 + threadIdx.x] = U1_1[d * 9 + threadIdx.x];
    float w3b[12], w2b[4];
#pragma unroll
    for (int k = 0; k < 12; ++k) w3b[k] = w3_1[(e * 12 + k) * CCH + c];
#pragma unroll
    for (int k = 0; k < 4; ++k)  w2b[k] = w2_1[(e * 4 + k) * CCH + c];
    __syncthreads();
    float* Td = T + (d + 1) * 972;
    for (int idx = threadIdx.x; idx < 972; idx += BLK) {
      int row = idx / 12, w = idx % 12;
      float acc = 0.f;
      if (w < 9) {
        int r = row * 9 + w;
#pragma unroll
        for (int k = 0; k < 12; ++k) acc += Us[r * 12 + k] * w3b[k];
      } else if (w == 9) {
#pragma unroll
        for (int k = 0; k < 4; ++k) acc += Us[U3LDS + row * 4 + k] * w2b[k];
      }
      Td[idx] = acc;
    }
    if (threadIdx.x < 9)
      T[T1OFF + (d + 1) * 9 + threadIdx.x] =
          Us[U3LDS + 324 + threadIdx.x] * w1_1[e * CCH + c];
  }
}

// ------------------------------------------------------- symmetric contraction
__global__ __launch_bounds__(BLK, 3) void contract_kernel(
    const float* __restrict__ feats, const float* __restrict__ table,
    const int* __restrict__ order, const int* __restrict__ offs,
    float* __restrict__ tmp, int NPAD) {
  const int c = blockIdx.y, e = blockIdx.z;
  const int start = offs[e], end = offs[e + 1];
  const int base = start + blockIdx.x * (BLK * NPT);
  if (base >= end) return;                      // block-uniform early exit

  __shared__ float T[TSTRIDE];
  {
    const float4* src = (const float4*)(table + (size_t)(e * CCH + c) * TSTRIDE);
    float4* dst = (float4*)T;
    for (int i = threadIdx.x; i < TSTRIDE / 4; i += BLK) dst[i] = src[i];
  }
  __syncthreads();

  const int tid = threadIdx.x;
  float x[NPT][LDIM];
  int pp[NPT];
  bool valid[NPT];
#pragma unroll
  for (int i = 0; i < NPT; ++i) {
    int p = base + i * BLK + tid;
    valid[i] = (p < end);
    int p2 = valid[i] ? p : (end - 1);          // clamp: stay in-bounds
    pp[i] = p;
    int n = order[p2];
    const float* xp = feats + ((size_t)n * CCH + c) * LDIM;
#pragma unroll
    for (int w = 0; w < LDIM; ++w) x[i][w] = xp[w];
  }

#pragma unroll 1
  for (int dd = 0; dd < 4; ++dd) {
    const float* T3d = T + dd * 972;
    const float* T1d = T + T1OFF + dd * 9;
    float accd[NPT];
#pragma unroll
    for (int i = 0; i < NPT; ++i) accd[i] = 0.f;
#pragma unroll 1
    for (int u = 0; u < 9; ++u) {
      // xu[i] = x[i][u] via select chain (u is runtime; structure compile-time)
      float xu[NPT];
#pragma unroll
      for (int i = 0; i < NPT; ++i) {
        float t = x[i][0];
#pragma unroll
        for (int k = 1; k < 9; ++k) t = (u == k) ? x[i][k] : t;
        xu[i] = t;
      }
      float t1 = T1d[u];
      float accu[NPT];
#pragma unroll
      for (int i = 0; i < NPT; ++i) accu[i] = t1;
      const float* Trow = T3d + u * 108;        // 9 rows * 12 floats
#pragma unroll
      for (int v = 0; v < 9; ++v) {
        const float4* r4 = (const float4*)(Trow + v * 12);
        float4 r0 = r4[0];
        float4 r1 = r4[1];
        float2 r2 = *(const float2*)(Trow + v * 12 + 8);  // {w8, t2}
#pragma unroll
        for (int i = 0; i < NPT; ++i) {
          float a = fmaf(x[i][0], r0.x, r2.y);
          a = fmaf(x[i][1], r0.y, a);
          a = fmaf(x[i][2], r0.z, a);
          a = fmaf(x[i][3], r0.w, a);
          a = fmaf(x[i][4], r1.x, a);
          a = fmaf(x[i][5], r1.y, a);
          a = fmaf(x[i][6], r1.z, a);
          a = fmaf(x[i][7], r1.w, a);
          a = fmaf(x[i][8], r2.x, a);
          accu[i] = fmaf(a, x[i][v], accu[i]);  // v compile-time
        }
      }
#pragma unroll
      for (int i = 0; i < NPT; ++i) accd[i] = fmaf(accu[i], xu[i], accd[i]);
    }
    float* o = tmp + (size_t)(dd * CCH + c) * NPAD;
#pragma unroll
    for (int i = 0; i < NPT; ++i)
      if (valid[i]) o[pp[i]] = accd[i];         // consecutive p -> coalesced
  }
}

// ---------------------- o3.Linear + residual (all dd fused, coalesced writes)
#define NB 16                 // nodes per block
__global__ __launch_bounds__(BLK, 4) void linear_kernel(
    const float* __restrict__ tmp, const float* __restrict__ W0,
    const float* __restrict__ W1, const float* __restrict__ sc,
    const int* __restrict__ order, float* __restrict__ out, int N, int NPAD) {
  const int p0 = blockIdx.x * NB;
  const int co = threadIdx.x & (CCH - 1);
  const int h  = threadIdx.x >> 7;              // 0/1: nodes p0+h*8 .. +8
  __shared__ float S[NB][516];                  // 512 + 4 pad

  float acc[4][8];
#pragma unroll
  for (int dd = 0; dd < 4; ++dd)
#pragma unroll
    for (int j = 0; j < 8; ++j) acc[dd][j] = 0.f;

  const int pbase = p0 + h * 8;
#pragma unroll 2
  for (int ci = 0; ci < CCH; ++ci) {
    float w0v = W0[ci * CCH + co];              // coalesced across lanes
    float w1v = W1[ci * CCH + co];
#pragma unroll
    for (int dd = 0; dd < 4; ++dd) {
      const float4* row =
          (const float4*)(tmp + (size_t)(dd * CCH + ci) * NPAD + pbase);
      float4 a0 = row[0], a1 = row[1];          // wave-uniform -> broadcast
      float wv = (dd == 0) ? w0v : w1v;
      acc[dd][0] = fmaf(a0.x, wv, acc[dd][0]);
      acc[dd][1] = fmaf(a0.y, wv, acc[dd][1]);
      acc[dd][2] = fmaf(a0.z, wv, acc[dd][2]);
      acc[dd][3] = fmaf(a0.w, wv, acc[dd][3]);
      acc[dd][4] = fmaf(a1.x, wv, acc[dd][4]);
      acc[dd][5] = fmaf(a1.y, wv, acc[dd][5]);
      acc[dd][6] = fmaf(a1.z, wv, acc[dd][6]);
      acc[dd][7] = fmaf(a1.w, wv, acc[dd][7]);
    }
  }

  const float s = 0.08838834764831843f;         // 1/sqrt(128)
#pragma unroll
  for (int j = 0; j < 8; ++j) {
    int node = h * 8 + j;
    S[node][co]               = acc[0][j] * s;  // stride-1: conflict-free
    S[node][CCH + co * 3 + 0] = acc[1][j] * s;  // stride-3: odd -> 2-way max
    S[node][CCH + co * 3 + 1] = acc[2][j] * s;
    S[node][CCH + co * 3 + 2] = acc[3][j] * s;
  }
  __syncthreads();

  // sc + write: full 512-float rows, float4-coalesced (128 lanes x 16B)
  const int f = threadIdx.x & 127;              // float4 index within row
  const int jj = threadIdx.x >> 7;
#pragma unroll 1
  for (int j = jj; j < NB; j += 2) {
    int p = p0 + j;
    if (p < N) {
      int n = order[p];
      float4 sv = ((const float4*)(sc + (size_t)n * 512))[f];
      float4 ov = ((const float4*)&S[j][0])[f];
      ov.x += sv.x; ov.y += sv.y; ov.z += sv.z; ov.w += sv.w;
      ((float4*)(out + (size_t)n * 512))[f] = ov;
    }
  }
}

// -------------------------------------------------------------------- launch
extern "C" void kernel_launch(void* const* d_in, const int* in_sizes, int n_in,
                              void* d_out, int out_size, void* d_ws, size_t ws_size,
                              hipStream_t stream) {
  const float* feats = (const float*)d_in[0];
  const float* attrs = (const float*)d_in[1];
  const float* sc    = (const float*)d_in[2];
  const float* U3_0  = (const float*)d_in[3];
  const float* U2_0  = (const float*)d_in[4];
  const float* U1_0  = (const float*)d_in[5];
  const float* w3_0  = (const float*)d_in[6];
  const float* w2_0  = (const float*)d_in[7];
  const float* w1_0  = (const float*)d_in[8];
  const float* U3_1  = (const float*)d_in[9];
  const float* U2_1  = (const float*)d_in[10];
  const float* U1_1  = (const float*)d_in[11];
  const float* w3_1  = (const float*)d_in[12];
  const float* w2_1  = (const float*)d_in[13];
  const float* w1_1  = (const float*)d_in[14];
  const float* W0    = (const float*)d_in[15];
  const float* W1    = (const float*)d_in[16];

  const int N = in_sizes[0] / (CCH * LDIM);     // 10000
  const int NPAD = ((N + 15) & ~15) + 16;

  // workspace (floats): tables | tmp[4*C][NPAD] | order[N] elem[N] offs[8] cur[8] gcnt[8]
  float* table = (float*)d_ws;
  float* tmp   = table + (size_t)NE * CCH * TSTRIDE;
  int*   order = (int*)(tmp + (size_t)4 * CCH * NPAD);
  int*   elem  = order + N;
  int*   offs  = elem + N;
  int*   cur   = offs + 8;
  int*   gcnt  = cur + 8;
  float* out   = (float*)d_out;

  hipMemsetAsync(gcnt, 0, NE * sizeof(int), stream);

  const int nblk = (N + BLK - 1) / BLK;
  count_kernel<<<dim3(nblk), dim3(BLK), 0, stream>>>(attrs, N, elem, gcnt);
  offs_kernel<<<dim3(1), dim3(64), 0, stream>>>(gcnt, offs, cur);
  scatter_kernel<<<dim3(nblk), dim3(BLK), 0, stream>>>(elem, N, cur, order);

  table_kernel<<<dim3(NE * CCH), dim3(BLK), 0, stream>>>(
      U3_0, U2_0, U1_0, U3_1, U2_1, U1_1,
      w3_0, w2_0, w1_0, w3_1, w2_1, w1_1, table);

  const int chunks = (N + BLK * NPT - 1) / (BLK * NPT);
  contract_kernel<<<dim3(chunks, CCH, NE), dim3(BLK), 0, stream>>>(
      feats, table, order, offs, tmp, NPAD);

  linear_kernel<<<dim3((N + NB - 1) / NB), dim3(BLK), 0, stream>>>(
      tmp, W0, W1, sc, order, out, N, NPAD);
}